// Round 14
// baseline (314.392 us; speedup 1.0000x reference)
//
#include <hip/hip_runtime.h>

// PWC-Net cost volume, fp32. B=4, C=128, H=256, W=448, 81 shifts.
// out[b, di*9+dj, h, w] = (1/128) * sum_c feat1[b,c,h,w] * feat2[b,c,h+di-4,w+dj-4]
//
// Barrier-free, LDS-free. One wave per (b,h,di,half): 18432 waves. Lane owns
// 4 px (G = half*56 + lane, 56 active). Per channel: 1 feat1 quad + 1 feat2
// quad per lane (b128, coalesced, zero overlap); window = left|own|right
// quads, neighbors via 8 ds_bpermute. Lanes 56/57 load boundary groups so
// pulls stay in-wave; edge garbage masked at store; OOB rows store zeros.
//
// THREE-STAGE SOFTWARE PIPELINE (all latencies covered):
//   iter t: LOAD ch t+2 (global, dist-2) |
//           BUILD window ch t+1 (bperm on data loaded at t-1, settled) |
//           FMA ch t (window built at t-1 -> never waits on DS latency).
// Load sets rotate period-3 (x,y,z); window banks ping-pong period-2 (A,B);
// body unrolled period-6 -> zero register moves. Middle window quad is read
// directly from the live load set (overwritten only at t+2).

typedef __attribute__((ext_vector_type(4))) float f32x4;

__device__ __forceinline__ float bperm(int idx, float v) {
    return __int_as_float(__builtin_amdgcn_ds_bpermute(idx, __float_as_int(v)));
}

__global__ __launch_bounds__(256, 5) void cv_kernel(
    const float* __restrict__ feat1,
    const float* __restrict__ feat2,
    float* __restrict__ out)
{
    constexpr int C = 128, H = 256, W = 448;
    constexpr unsigned HW = (unsigned)(H * W);

    const int tid  = threadIdx.x;
    const int wid  = tid >> 6;
    const int lane = tid & 63;

    // 4608 blocks = 8 * 576: XCD-contiguous item mapping (bijective).
    const int swz   = (blockIdx.x & 7) * 576 + (blockIdx.x >> 3);
    const int item2 = swz * 4 + wid;          // 0..18431
    const int half  = item2 & 1;
    const int item  = item2 >> 1;             // 0..9215
    const int di    = item % 9;
    const int bh    = item / 9;
    const int h     = bh & 255;
    const int b     = bh >> 8;

    const int mg = (lane < 56) ? lane : 55;   // local group 0..55
    const int G  = half * 56 + mg;            // global group 0..111
    const int hr = h + di - 4;

    float* ob = out + (((size_t)(b * 81 + di * 9)) * H + h) * W + G * 4;

    if (hr < 0 || hr >= H) {                  // wave-uniform: whole row zero
        if (lane < 56) {
            const f32x4 z = {0.f, 0.f, 0.f, 0.f};
#pragma unroll
            for (int dj = 0; dj < 9; ++dj)
                *(f32x4*)(ob + (size_t)dj * HW) = z;
        }
        return;
    }

    // Load-group: lanes 0..55 own; 56 = right-boundary; 57 = left-boundary.
    int gload;
    if (half == 0) gload = (lane < 56) ? lane : (lane == 56 ? 56 : (lane == 57 ? 0 : 55));
    else           gload = (lane < 56) ? 56 + lane : (lane == 56 ? 111 : (lane == 57 ? 55 : 60));

    unsigned f1o = (unsigned)(((b * C * H) + h) * W + gload * 4);
    unsigned f2o = (unsigned)(((b * C * H) + hr) * W + gload * 4);

    const int idxL = ((lane == 0)  ? 57 : lane - 1) << 2;
    const int idxR = ((lane == 55) ? 56 : lane + 1) << 2;

    float acc[9][4];
#pragma unroll
    for (int j = 0; j < 9; ++j)
#pragma unroll
        for (int p = 0; p < 4; ++p) acc[j][p] = 0.0f;

    // Load sets (period-3) and window banks A/B (period-2), named scalars.
    f32x4 xa, xb, ya, yb, za, zb;
    float AL0, AL1, AL2, AL3, AR0, AR1, AR2, AR3;
    float BL0, BL1, BL2, BL3, BR0, BR1, BR2, BR3;

#define LOADSET(A, Bv) do { \
    A  = *(const f32x4*)(feat1 + f1o); \
    Bv = *(const f32x4*)(feat2 + f2o); \
    f1o += HW; f2o += HW; } while (0)

// BK is a literal bank letter (A or B); token-pasted into scalar names.
#define BUILDW(BK, Bv) do { \
    BK##L0 = bperm(idxL, Bv.x); BK##L1 = bperm(idxL, Bv.y); \
    BK##L2 = bperm(idxL, Bv.z); BK##L3 = bperm(idxL, Bv.w); \
    BK##R0 = bperm(idxR, Bv.x); BK##R1 = bperm(idxR, Bv.y); \
    BK##R2 = bperm(idxR, Bv.z); BK##R3 = bperm(idxR, Bv.w); } while (0)

#define FMASET(A, Bv, BK) do { \
    const float w[12] = {BK##L0, BK##L1, BK##L2, BK##L3, \
                         Bv.x, Bv.y, Bv.z, Bv.w, \
                         BK##R0, BK##R1, BK##R2, BK##R3}; \
    const float a[4] = {A.x, A.y, A.z, A.w}; \
    _Pragma("unroll") \
    for (int dj = 0; dj < 9; ++dj) { \
        _Pragma("unroll") \
        for (int p = 0; p < 4; ++p) \
            acc[dj][p] = fmaf(a[p], w[dj + p], acc[dj][p]); \
    } } while (0)

    // Prologue: load ch0,ch1; build window(ch0) -> bank A.
    LOADSET(xa, xb);                 // ch 0 -> set x
    LOADSET(ya, yb);                 // ch 1 -> set y
    BUILDW(A, xb);                   // window(0) in bank A

    // Main loop: t = 0..125, period-6 unroll (21 iters). Body t:
    //   LOAD ch t+2 -> set (t+2)%3 ; BUILD win(t+1) from set (t+1)%3 -> bank (t+1)%2 ;
    //   FMA ch t: set t%3, bank t%2.
    for (int g = 0; g < 21; ++g) {
        LOADSET(za, zb); BUILDW(B, yb); FMASET(xa, xb, A);   // t=6g+0
        LOADSET(xa, xb); BUILDW(A, zb); FMASET(ya, yb, B);   // t=6g+1
        LOADSET(ya, yb); BUILDW(B, xb); FMASET(za, zb, A);   // t=6g+2
        LOADSET(za, zb); BUILDW(A, yb); FMASET(xa, xb, B);   // t=6g+3
        LOADSET(xa, xb); BUILDW(B, zb); FMASET(ya, yb, A);   // t=6g+4
        LOADSET(ya, yb); BUILDW(A, xb); FMASET(za, zb, B);   // t=6g+5
    }
    // Epilogue: t=126 (set x, bank A; build win(127) from y -> bank B), t=127.
    BUILDW(B, yb); FMASET(xa, xb, A);                        // t=126
    FMASET(ya, yb, B);                                       // t=127

#undef LOADSET
#undef BUILDW
#undef FMASET

    if (lane < 56) {
        const float s = 1.0f / 128.0f;
        const bool leftEdge  = (G == 0);
        const bool rightEdge = (G == 111);
#pragma unroll
        for (int dj = 0; dj < 9; ++dj) {
            float o[4];
#pragma unroll
            for (int p = 0; p < 4; ++p) {
                float v = acc[dj][p] * s;
                // out col = 4G + p + dj - 4: left-quad garbage -> dj+p<4,
                // right-quad garbage -> dj+p>7.
                if (dj + p < 4) v = leftEdge  ? 0.f : v;
                if (dj + p > 7) v = rightEdge ? 0.f : v;
                o[p] = v;
            }
            f32x4 ov = {o[0], o[1], o[2], o[3]};
            *(f32x4*)(ob + (size_t)dj * HW) = ov;
        }
    }
}

extern "C" void kernel_launch(void* const* d_in, const int* in_sizes, int n_in,
                              void* d_out, int out_size, void* d_ws, size_t ws_size,
                              hipStream_t stream) {
    const float* feat1 = (const float*)d_in[0];
    const float* feat2 = (const float*)d_in[1];
    float* out = (float*)d_out;
    cv_kernel<<<dim3(4608), dim3(256), 0, stream>>>(feat1, feat2, out);
}